// Round 8
// baseline (134.744 us; speedup 1.0000x reference)
//
#include <hip/hip_runtime.h>
#include <math.h>

#define T   1024   // threads per block (16 waves)
#define NB  512    // blocks for k_stats / k_loss (2 blocks/CU -> 32 waves/CU)

// ---- monotone float <-> uint encoding (order-preserving) ----
__device__ __forceinline__ unsigned enc_f(float f) {
    unsigned b = __float_as_uint(f);
    return (b & 0x80000000u) ? ~b : (b | 0x80000000u);
}
__device__ __forceinline__ float dec_f(unsigned u) {
    unsigned b = (u & 0x80000000u) ? (u ^ 0x80000000u) : ~u;
    return __uint_as_float(b);
}
#define ENC_NEG_INF 0x007FFFFFu   // enc(-inf): identity for max
#define ENC_POS_INF 0xFF800000u   // enc(+inf): identity for min
// word w in a 32-word record: [0..7] gmax(max) [8..15] pmin(min) [16..23] zmin(min) [24..31] zmax(max)
__device__ __forceinline__ unsigned ident_w(int w) {
    return (w < 8 || w >= 24) ? ENC_NEG_INF : ENC_POS_INF;
}

// ws layout (unsigned words) — NO device-scope atomics anywhere; every cross-block
// value crosses a kernel boundary (plain loads/stores, coherent at dispatch edges):
//   [64 + blk*32 + w]   per-block stat records, NB blocks        (k_stats -> k_loss)
//   [PART_W + blk]      per-block float partial sums, NB blocks  (k_loss -> k_final)
//   [ZOFF_W ..]         staged z, N floats   (byte offset 4 MB)  (k_stats -> k_loss)
//   [SOFF_W ..]         staged seg, 1 B/pt   (byte offset 32 MB) (k_stats -> k_loss)
#define SLOT(base, blk) ((base) + 64 + (blk) * 32)
#define PART_W  20000u
#define ZOFF_W (1u << 20)
#define SOFF_W (8u << 20)

#define CNT_B(ii, bdst) do { bdst = 0; \
    _Pragma("unroll") for (int j_ = 0; j_ < 8; ++j_) bdst += ((ii) >= roff[j_]); } while (0)

#define FLUSH_LDS(bb, g_, p_, mn_, mx_) do { \
    atomicMax(&s_stats[      (bb)], enc_f(g_));  \
    atomicMin(&s_stats[ 8  + (bb)], enc_f(p_));  \
    atomicMin(&s_stats[16  + (bb)], enc_f(mn_)); \
    atomicMax(&s_stats[24  + (bb)], enc_f(mx_)); } while (0)

// stats update for one 4-pt group (z0..z3 from coord f4 triple, s from int4)
#define STAT4(z0, z1, z2, z3, s) do { \
    lmn = fminf(lmn, fminf(fminf(z0, z1), fminf(z2, z3))); \
    lmx = fmaxf(lmx, fmaxf(fmaxf(z0, z1), fmaxf(z2, z3))); \
    lg = fmaxf(lg, ((s).x == 0) ? z0 : -INFINITY); \
    lg = fmaxf(lg, ((s).y == 0) ? z1 : -INFINITY); \
    lg = fmaxf(lg, ((s).z == 0) ? z2 : -INFINITY); \
    lg = fmaxf(lg, ((s).w == 0) ? z3 : -INFINITY); \
    lp = fminf(lp, ((s).x != 0) ? z0 : INFINITY); \
    lp = fminf(lp, ((s).y != 0) ? z1 : INFINITY); \
    lp = fminf(lp, ((s).z != 0) ? z2 : INFINITY); \
    lp = fminf(lp, ((s).w != 0) ? z3 : INFINITY); } while (0)

__device__ __forceinline__ float point_loss(float p0, float p1, int s, float z, float mu) {
    float m   = fmaxf(p0, p1);
    float lse = m + logf(expf(p0 - m) + expf(p1 - m));
    float lpt = ((s == 0) ? p0 : p1) - lse;
    float pt  = expf(lpt);
    float om  = 1.0f - pt;
    float loss = -lpt * om * om;           // LOSS_WEIGHT=ALPHA=1, GAMMA=2
    float d  = z - mu;
    float cf = (z <= mu) ? 50.0f : 3.125f; // 1/(2*0.1^2), 1/(2*0.4^2)
    float w  = expf(-d * d * cf);
    if (z > mu && d > 0.8f) w = 0.1f;      // d > 2*0.4 -> MIN_VAL
    return loss * w;
}

// Pass 1: stats over (z, segment); unroll-jam 2 groups (8 pts/thread/iter) with all
// 8 vector loads issued up front (MLP). Stages compact z (f32) + seg (1 B) into ws.
// Plain stores only; kernel boundary = coherence.
__global__ __launch_bounds__(T, 8) void k_stats(
        const float* __restrict__ coord, const int* __restrict__ segment,
        const int* __restrict__ offset, unsigned* __restrict__ ws, int n, int nb) {
    __shared__ unsigned s_stats[32];
    const int tid = threadIdx.x;
    if (tid < 32) s_stats[tid] = ident_w(tid);
    int roff[8];
    #pragma unroll
    for (int j = 0; j < 8; ++j) roff[j] = (j < nb) ? offset[j] : 0x7FFFFFFF;
    __syncthreads();

    int chunk = (n + (int)gridDim.x - 1) / (int)gridDim.x;
    chunk = (chunk + 3) & ~3;                       // keep 4-point alignment
    const int start = blockIdx.x * chunk;
    const int end   = min(n, start + chunk);

    float*         zs = (float*)(ws + ZOFF_W);
    unsigned char* sb = (unsigned char*)(ws + SOFF_W);

    if (start < end) {
        int ba = 0, bb = 0;
        #pragma unroll
        for (int j = 0; j < 8; ++j) { ba += (start >= roff[j]); bb += ((end - 1) >= roff[j]); }
        float lg = -INFINITY, lp = INFINITY, lmn = INFINITY, lmx = -INFINITY;

        if (ba == bb && ((end - start) % (4 * T) == 0)) {
            const float4* c4 = (const float4*)coord;
            const int4*   s4 = (const int4*)segment;
            float4*       z4 = (float4*)zs;
            unsigned*     sw = (unsigned*)sb;
            int p0 = start;
            for (; p0 + 8 * T <= end; p0 += 8 * T) {    // jam: 2 groups, 8 loads in flight
                const int q0 = (p0 >> 2) + tid, q1 = q0 + T;
                float4 a0 = c4[3 * q0 + 0], b0 = c4[3 * q0 + 1], c0 = c4[3 * q0 + 2];
                float4 a1 = c4[3 * q1 + 0], b1 = c4[3 * q1 + 1], c1 = c4[3 * q1 + 2];
                int4   s0 = s4[q0],        s1 = s4[q1];
                const float x0 = a0.z, x1 = b0.y, x2 = c0.x, x3 = c0.w;
                z4[q0] = make_float4(x0, x1, x2, x3);
                sw[q0] = (unsigned)(s0.x & 1) | ((unsigned)(s0.y & 1) << 8)
                       | ((unsigned)(s0.z & 1) << 16) | ((unsigned)(s0.w & 1) << 24);
                STAT4(x0, x1, x2, x3, s0);
                const float y0 = a1.z, y1 = b1.y, y2 = c1.x, y3 = c1.w;
                z4[q1] = make_float4(y0, y1, y2, y3);
                sw[q1] = (unsigned)(s1.x & 1) | ((unsigned)(s1.y & 1) << 8)
                       | ((unsigned)(s1.z & 1) << 16) | ((unsigned)(s1.w & 1) << 24);
                STAT4(y0, y1, y2, y3, s1);
            }
            for (; p0 < end; p0 += 4 * T) {             // <=1 leftover group
                const int q = (p0 >> 2) + tid;
                float4 a = c4[3 * q + 0], b = c4[3 * q + 1], c = c4[3 * q + 2];
                int4   s = s4[q];
                const float x0 = a.z, x1 = b.y, x2 = c.x, x3 = c.w;
                z4[q] = make_float4(x0, x1, x2, x3);
                sw[q] = (unsigned)(s.x & 1) | ((unsigned)(s.y & 1) << 8)
                      | ((unsigned)(s.z & 1) << 16) | ((unsigned)(s.w & 1) << 24);
                STAT4(x0, x1, x2, x3, s);
            }
            #pragma unroll
            for (int m = 32; m; m >>= 1) {
                lg  = fmaxf(lg,  __shfl_xor(lg,  m, 64));
                lp  = fminf(lp,  __shfl_xor(lp,  m, 64));
                lmn = fminf(lmn, __shfl_xor(lmn, m, 64));
                lmx = fmaxf(lmx, __shfl_xor(lmx, m, 64));
            }
            if ((tid & 63) == 0) FLUSH_LDS(ba, lg, lp, lmn, lmx);
        } else {
            // slow path (boundary/partial blocks): scalar, per-point batch tracking
            int curb = -1;
            for (int i = start + tid; i < end; i += T) {
                float z = coord[3 * i + 2]; int s = segment[i], b;
                zs[i] = z;
                sb[i] = (unsigned char)(s & 1);
                CNT_B(i, b);
                if (b != curb) {
                    if (curb >= 0) FLUSH_LDS(curb, lg, lp, lmn, lmx);
                    lg = -INFINITY; lp = INFINITY; lmn = INFINITY; lmx = -INFINITY;
                    curb = b;
                }
                lmn = fminf(lmn, z); lmx = fmaxf(lmx, z);
                if (s == 0) lg = fmaxf(lg, z); else lp = fminf(lp, z);
            }
            if (curb >= 0) FLUSH_LDS(curb, lg, lp, lmn, lmx);
        }
    }
    __syncthreads();
    if (tid < 32) SLOT(ws, blockIdx.x)[tid] = s_stats[tid];   // plain store
}

// Pass 2: combine records -> mu; loss from pred + staged z/seg (unroll-jam 2 groups).
// Ends with ONE plain store of the per-block partial — no atomics, no fences.
__global__ __launch_bounds__(T, 8) void k_loss(
        const float* __restrict__ pred, const int* __restrict__ offset,
        unsigned* __restrict__ ws, int n, int nb) {
    __shared__ unsigned s_comb[32];
    __shared__ float    s_mu[8];
    __shared__ float    s_part[T / 64];
    const int tid = threadIdx.x;
    int roff[8];
    #pragma unroll
    for (int j = 0; j < 8; ++j) roff[j] = (j < nb) ? offset[j] : 0x7FFFFFFF;

    // ---- reduce the NB per-block stat records (coalesced reads + LDS atomics) ----
    if (tid < 32) s_comb[tid] = ident_w(tid);
    __syncthreads();
    {
        const int w = tid & 31, g = tid >> 5;          // 32 groups x 32 words
        unsigned v = ident_w(w);
        #pragma unroll
        for (int j = 0; j < NB / 32; ++j) {
            unsigned u = SLOT((const unsigned*)ws, g * (NB / 32) + j)[w];
            v = (w < 8 || w >= 24) ? max(v, u) : min(v, u);
        }
        if (w < 8 || w >= 24) atomicMax(&s_comb[w], v);
        else                  atomicMin(&s_comb[w], v);
    }
    __syncthreads();
    if (tid < 8) {
        unsigned ug = s_comb[tid], up = s_comb[8 + tid];
        float g = dec_f(ug), p = dec_f(up);
        if (ug == ENC_NEG_INF) g = dec_f(s_comb[16 + tid]);  // no ground -> z.min
        if (up == ENC_POS_INF) p = dec_f(s_comb[24 + tid]);  // no plant  -> z.max
        s_mu[tid] = g + (p - g) * 0.5f;
    }
    __syncthreads();

    int chunk = (n + (int)gridDim.x - 1) / (int)gridDim.x;
    chunk = (chunk + 3) & ~3;
    const int start = blockIdx.x * chunk;
    const int end   = min(n, start + chunk);

    const float*         zs  = (const float*)(ws + ZOFF_W);
    const unsigned char* sbB = (const unsigned char*)(ws + SOFF_W);

    float lsum = 0.0f;
    if (start < end) {
        int ba = 0, bb = 0;
        #pragma unroll
        for (int j = 0; j < 8; ++j) { ba += (start >= roff[j]); bb += ((end - 1) >= roff[j]); }

        if (ba == bb && ((end - start) % (4 * T) == 0)) {
            const float mu = s_mu[ba];
            const float4*   p4 = (const float4*)pred;
            const float4*   z4 = (const float4*)zs;
            const unsigned* sw = (const unsigned*)sbB;
            int p0 = start;
            for (; p0 + 8 * T <= end; p0 += 8 * T) {    // jam: 8 loads in flight
                const int q0 = (p0 >> 2) + tid, q1 = q0 + T;
                float4 pa0 = p4[2 * q0 + 0], pb0 = p4[2 * q0 + 1];
                float4 pa1 = p4[2 * q1 + 0], pb1 = p4[2 * q1 + 1];
                float4 zz0 = z4[q0],         zz1 = z4[q1];
                unsigned sA = sw[q0],        sB = sw[q1];
                lsum += point_loss(pa0.x, pa0.y, (int)( sA        & 1u), zz0.x, mu);
                lsum += point_loss(pa0.z, pa0.w, (int)((sA >>  8) & 1u), zz0.y, mu);
                lsum += point_loss(pb0.x, pb0.y, (int)((sA >> 16) & 1u), zz0.z, mu);
                lsum += point_loss(pb0.z, pb0.w, (int)((sA >> 24) & 1u), zz0.w, mu);
                lsum += point_loss(pa1.x, pa1.y, (int)( sB        & 1u), zz1.x, mu);
                lsum += point_loss(pa1.z, pa1.w, (int)((sB >>  8) & 1u), zz1.y, mu);
                lsum += point_loss(pb1.x, pb1.y, (int)((sB >> 16) & 1u), zz1.z, mu);
                lsum += point_loss(pb1.z, pb1.w, (int)((sB >> 24) & 1u), zz1.w, mu);
            }
            for (; p0 < end; p0 += 4 * T) {
                const int q = (p0 >> 2) + tid;
                float4 pa = p4[2 * q + 0], pb = p4[2 * q + 1];
                float4 zz = z4[q];
                unsigned s = sw[q];
                lsum += point_loss(pa.x, pa.y, (int)( s        & 1u), zz.x, mu);
                lsum += point_loss(pa.z, pa.w, (int)((s >>  8) & 1u), zz.y, mu);
                lsum += point_loss(pb.x, pb.y, (int)((s >> 16) & 1u), zz.z, mu);
                lsum += point_loss(pb.z, pb.w, (int)((s >> 24) & 1u), zz.w, mu);
            }
        } else {
            const float2* pred2 = (const float2*)pred;
            for (int i = start + tid; i < end; i += T) {
                int b; CNT_B(i, b);
                float2 pp = pred2[i];
                lsum += point_loss(pp.x, pp.y, (int)sbB[i], zs[i], s_mu[b]);
            }
        }
    }

    #pragma unroll
    for (int off = 32; off > 0; off >>= 1) lsum += __shfl_down(lsum, off, 64);
    if ((tid & 63) == 0) s_part[tid >> 6] = lsum;
    __syncthreads();
    if (tid == 0) {
        float t = 0.0f;
        #pragma unroll
        for (int wv = 0; wv < T / 64; ++wv) t += s_part[wv];
        ((float*)(ws + PART_W))[blockIdx.x] = t;   // private slot, plain store
    }
}

// Pass 3: one tiny block sums the NB partials in double and writes the mean.
__global__ __launch_bounds__(NB) void k_final(
        const unsigned* __restrict__ ws, float* __restrict__ out, int n) {
    __shared__ float sp[NB];
    const int tid = threadIdx.x;
    sp[tid] = ((const float*)(ws + PART_W))[tid];
    __syncthreads();
    if (tid == 0) {
        double v = 0.0;
        for (int i = 0; i < NB; ++i) v += (double)sp[i];
        out[0] = (float)(v / (double)n);
    }
}

extern "C" void kernel_launch(void* const* d_in, const int* in_sizes, int n_in,
                              void* d_out, int out_size, void* d_ws, size_t ws_size,
                              hipStream_t stream) {
    const float* pred    = (const float*)d_in[0];
    const float* coord   = (const float*)d_in[1];
    const int*   segment = (const int*)d_in[2];
    const int*   offset  = (const int*)d_in[3];
    const int n  = in_sizes[2];
    const int nb = in_sizes[3];
    unsigned* ws = (unsigned*)d_ws;

    hipLaunchKernelGGL(k_stats, dim3(NB), dim3(T), 0, stream,
                       coord, segment, offset, ws, n, nb);
    hipLaunchKernelGGL(k_loss, dim3(NB), dim3(T), 0, stream,
                       pred, offset, ws, n, nb);
    hipLaunchKernelGGL(k_final, dim3(1), dim3(NB), 0, stream,
                       ws, (float*)d_out, n);
}

// Round 9
// 129.609 us; speedup vs baseline: 1.0396x; 1.0396x over previous
//
#include <hip/hip_runtime.h>
#include <math.h>

#define T   1024   // threads per block (16 waves)
#define NB  512    // blocks for k_stats / k_loss

// ---- monotone float <-> uint encoding (order-preserving) ----
__device__ __forceinline__ unsigned enc_f(float f) {
    unsigned b = __float_as_uint(f);
    return (b & 0x80000000u) ? ~b : (b | 0x80000000u);
}
__device__ __forceinline__ float dec_f(unsigned u) {
    unsigned b = (u & 0x80000000u) ? (u ^ 0x80000000u) : ~u;
    return __uint_as_float(b);
}
#define ENC_NEG_INF 0x007FFFFFu   // enc(-inf): identity for max
#define ENC_POS_INF 0xFF800000u   // enc(+inf): identity for min
// word w in a 32-word record: [0..7] gmax(max) [8..15] pmin(min) [16..23] zmin(min) [24..31] zmax(max)
__device__ __forceinline__ unsigned ident_w(int w) {
    return (w < 8 || w >= 24) ? ENC_NEG_INF : ENC_POS_INF;
}

// ws layout (unsigned words) — NO device-scope atomics, NO staging (minimal unique
// footprint: poison write-back debt scales with unique bytes touched). All
// cross-block values cross kernel boundaries (plain stores, coherent at edges):
//   [64 + blk*32 + w]   per-block stat records, NB blocks        (k_stats -> k_loss)
//   [PART_W + blk]      per-block float partial sums, NB blocks  (k_loss -> k_final)
#define SLOT(base, blk) ((base) + 64 + (blk) * 32)
#define PART_W  20000u

#define CNT_B(ii, bdst) do { bdst = 0; \
    _Pragma("unroll") for (int j_ = 0; j_ < 8; ++j_) bdst += ((ii) >= roff[j_]); } while (0)

#define FLUSH_LDS(bb, g_, p_, mn_, mx_) do { \
    atomicMax(&s_stats[      (bb)], enc_f(g_));  \
    atomicMin(&s_stats[ 8  + (bb)], enc_f(p_));  \
    atomicMin(&s_stats[16  + (bb)], enc_f(mn_)); \
    atomicMax(&s_stats[24  + (bb)], enc_f(mx_)); } while (0)

// stats update for one 4-pt group (z0..z3 from coord f4 triple, s from int4)
#define STAT4(z0, z1, z2, z3, s) do { \
    lmn = fminf(lmn, fminf(fminf(z0, z1), fminf(z2, z3))); \
    lmx = fmaxf(lmx, fmaxf(fmaxf(z0, z1), fmaxf(z2, z3))); \
    lg = fmaxf(lg, ((s).x == 0) ? z0 : -INFINITY); \
    lg = fmaxf(lg, ((s).y == 0) ? z1 : -INFINITY); \
    lg = fmaxf(lg, ((s).z == 0) ? z2 : -INFINITY); \
    lg = fmaxf(lg, ((s).w == 0) ? z3 : -INFINITY); \
    lp = fminf(lp, ((s).x != 0) ? z0 : INFINITY); \
    lp = fminf(lp, ((s).y != 0) ? z1 : INFINITY); \
    lp = fminf(lp, ((s).z != 0) ? z2 : INFINITY); \
    lp = fminf(lp, ((s).w != 0) ? z3 : INFINITY); } while (0)

__device__ __forceinline__ float point_loss(float p0, float p1, int s, float z, float mu) {
    float m   = fmaxf(p0, p1);
    float lse = m + logf(expf(p0 - m) + expf(p1 - m));
    float lpt = ((s == 0) ? p0 : p1) - lse;
    float pt  = expf(lpt);
    float om  = 1.0f - pt;
    float loss = -lpt * om * om;           // LOSS_WEIGHT=ALPHA=1, GAMMA=2
    float d  = z - mu;
    float cf = (z <= mu) ? 50.0f : 3.125f; // 1/(2*0.1^2), 1/(2*0.4^2)
    float w  = expf(-d * d * cf);
    if (z > mu && d > 0.8f) w = 0.1f;      // d > 2*0.4 -> MIN_VAL
    return loss * w;
}

// Pass 1: stats over (z, segment) with float4/int4 loads, 2-group jam.
// NO staging stores (unique-footprint minimization) — pass 2 re-reads the same
// lines from L3. Ends with a 32-word plain-store record.
__global__ __launch_bounds__(T, 8) void k_stats(
        const float* __restrict__ coord, const int* __restrict__ segment,
        const int* __restrict__ offset, unsigned* __restrict__ ws, int n, int nb) {
    __shared__ unsigned s_stats[32];
    const int tid = threadIdx.x;
    if (tid < 32) s_stats[tid] = ident_w(tid);
    int roff[8];
    #pragma unroll
    for (int j = 0; j < 8; ++j) roff[j] = (j < nb) ? offset[j] : 0x7FFFFFFF;
    __syncthreads();

    int chunk = (n + (int)gridDim.x - 1) / (int)gridDim.x;
    chunk = (chunk + 3) & ~3;                       // keep 4-point alignment
    const int start = blockIdx.x * chunk;
    const int end   = min(n, start + chunk);

    if (start < end) {
        int ba = 0, bb = 0;
        #pragma unroll
        for (int j = 0; j < 8; ++j) { ba += (start >= roff[j]); bb += ((end - 1) >= roff[j]); }
        float lg = -INFINITY, lp = INFINITY, lmn = INFINITY, lmx = -INFINITY;

        if (ba == bb && ((end - start) % (4 * T) == 0)) {
            const float4* c4 = (const float4*)coord;
            const int4*   s4 = (const int4*)segment;
            int p0 = start;
            for (; p0 + 8 * T <= end; p0 += 8 * T) {    // jam: 2 groups, 8 loads in flight
                const int q0 = (p0 >> 2) + tid, q1 = q0 + T;
                float4 a0 = c4[3 * q0 + 0], b0 = c4[3 * q0 + 1], c0 = c4[3 * q0 + 2];
                float4 a1 = c4[3 * q1 + 0], b1 = c4[3 * q1 + 1], c1 = c4[3 * q1 + 2];
                int4   s0 = s4[q0],        s1 = s4[q1];
                const float x0 = a0.z, x1 = b0.y, x2 = c0.x, x3 = c0.w;
                STAT4(x0, x1, x2, x3, s0);
                const float y0 = a1.z, y1 = b1.y, y2 = c1.x, y3 = c1.w;
                STAT4(y0, y1, y2, y3, s1);
            }
            for (; p0 < end; p0 += 4 * T) {             // <=1 leftover group
                const int q = (p0 >> 2) + tid;
                float4 a = c4[3 * q + 0], b = c4[3 * q + 1], c = c4[3 * q + 2];
                int4   s = s4[q];
                const float x0 = a.z, x1 = b.y, x2 = c.x, x3 = c.w;
                STAT4(x0, x1, x2, x3, s);
            }
            #pragma unroll
            for (int m = 32; m; m >>= 1) {
                lg  = fmaxf(lg,  __shfl_xor(lg,  m, 64));
                lp  = fminf(lp,  __shfl_xor(lp,  m, 64));
                lmn = fminf(lmn, __shfl_xor(lmn, m, 64));
                lmx = fmaxf(lmx, __shfl_xor(lmx, m, 64));
            }
            if ((tid & 63) == 0) FLUSH_LDS(ba, lg, lp, lmn, lmx);
        } else {
            // slow path (boundary/partial blocks): scalar, per-point batch tracking
            int curb = -1;
            for (int i = start + tid; i < end; i += T) {
                float z = coord[3 * i + 2]; int s = segment[i], b;
                CNT_B(i, b);
                if (b != curb) {
                    if (curb >= 0) FLUSH_LDS(curb, lg, lp, lmn, lmx);
                    lg = -INFINITY; lp = INFINITY; lmn = INFINITY; lmx = -INFINITY;
                    curb = b;
                }
                lmn = fminf(lmn, z); lmx = fmaxf(lmx, z);
                if (s == 0) lg = fmaxf(lg, z); else lp = fminf(lp, z);
            }
            if (curb >= 0) FLUSH_LDS(curb, lg, lp, lmn, lmx);
        }
    }
    __syncthreads();
    if (tid < 32) SLOT(ws, blockIdx.x)[tid] = s_stats[tid];   // plain store
}

// Pass 2: combine records -> mu; loss from pred (float4, HBM) + coord/segment
// re-read (float4/int4 — same lines as pass 1, L3-hot, no new HBM footprint).
// Ends with ONE plain store of the per-block partial — no atomics, no fences.
__global__ __launch_bounds__(T, 8) void k_loss(
        const float* __restrict__ pred, const float* __restrict__ coord,
        const int* __restrict__ segment, const int* __restrict__ offset,
        unsigned* __restrict__ ws, int n, int nb) {
    __shared__ unsigned s_comb[32];
    __shared__ float    s_mu[8];
    __shared__ float    s_part[T / 64];
    const int tid = threadIdx.x;
    int roff[8];
    #pragma unroll
    for (int j = 0; j < 8; ++j) roff[j] = (j < nb) ? offset[j] : 0x7FFFFFFF;

    // ---- reduce the NB per-block stat records (coalesced reads + LDS atomics) ----
    if (tid < 32) s_comb[tid] = ident_w(tid);
    __syncthreads();
    {
        const int w = tid & 31, g = tid >> 5;          // 32 groups x 32 words
        unsigned v = ident_w(w);
        #pragma unroll
        for (int j = 0; j < NB / 32; ++j) {
            unsigned u = SLOT((const unsigned*)ws, g * (NB / 32) + j)[w];
            v = (w < 8 || w >= 24) ? max(v, u) : min(v, u);
        }
        if (w < 8 || w >= 24) atomicMax(&s_comb[w], v);
        else                  atomicMin(&s_comb[w], v);
    }
    __syncthreads();
    if (tid < 8) {
        unsigned ug = s_comb[tid], up = s_comb[8 + tid];
        float g = dec_f(ug), p = dec_f(up);
        if (ug == ENC_NEG_INF) g = dec_f(s_comb[16 + tid]);  // no ground -> z.min
        if (up == ENC_POS_INF) p = dec_f(s_comb[24 + tid]);  // no plant  -> z.max
        s_mu[tid] = g + (p - g) * 0.5f;
    }
    __syncthreads();

    int chunk = (n + (int)gridDim.x - 1) / (int)gridDim.x;
    chunk = (chunk + 3) & ~3;
    const int start = blockIdx.x * chunk;
    const int end   = min(n, start + chunk);

    float lsum = 0.0f;
    if (start < end) {
        int ba = 0, bb = 0;
        #pragma unroll
        for (int j = 0; j < 8; ++j) { ba += (start >= roff[j]); bb += ((end - 1) >= roff[j]); }

        if (ba == bb && ((end - start) % (4 * T) == 0)) {
            const float mu = s_mu[ba];
            const float4* p4 = (const float4*)pred;
            const float4* c4 = (const float4*)coord;
            const int4*   s4 = (const int4*)segment;
            for (int p0 = start; p0 < end; p0 += 4 * T) {   // one 4-pt group / iter
                const int q = (p0 >> 2) + tid;
                float4 pa = p4[2 * q + 0], pb = p4[2 * q + 1];     // pred, HBM
                float4 a  = c4[3 * q + 0], b = c4[3 * q + 1], c = c4[3 * q + 2]; // L3
                int4   s  = s4[q];                                  // L3
                lsum += point_loss(pa.x, pa.y, s.x, a.z, mu);
                lsum += point_loss(pa.z, pa.w, s.y, b.y, mu);
                lsum += point_loss(pb.x, pb.y, s.z, c.x, mu);
                lsum += point_loss(pb.z, pb.w, s.w, c.w, mu);
            }
        } else {
            const float2* pred2 = (const float2*)pred;
            for (int i = start + tid; i < end; i += T) {
                int b; CNT_B(i, b);
                float2 pp = pred2[i];
                lsum += point_loss(pp.x, pp.y, segment[i], coord[3 * i + 2], s_mu[b]);
            }
        }
    }

    #pragma unroll
    for (int off = 32; off > 0; off >>= 1) lsum += __shfl_down(lsum, off, 64);
    if ((tid & 63) == 0) s_part[tid >> 6] = lsum;
    __syncthreads();
    if (tid == 0) {
        float t = 0.0f;
        #pragma unroll
        for (int wv = 0; wv < T / 64; ++wv) t += s_part[wv];
        ((float*)(ws + PART_W))[blockIdx.x] = t;   // private slot, plain store
    }
}

// Pass 3: one tiny block sums the NB partials in double and writes the mean.
__global__ __launch_bounds__(NB) void k_final(
        const unsigned* __restrict__ ws, float* __restrict__ out, int n) {
    __shared__ float sp[NB];
    const int tid = threadIdx.x;
    sp[tid] = ((const float*)(ws + PART_W))[tid];
    __syncthreads();
    if (tid == 0) {
        double v = 0.0;
        for (int i = 0; i < NB; ++i) v += (double)sp[i];
        out[0] = (float)(v / (double)n);
    }
}

extern "C" void kernel_launch(void* const* d_in, const int* in_sizes, int n_in,
                              void* d_out, int out_size, void* d_ws, size_t ws_size,
                              hipStream_t stream) {
    const float* pred    = (const float*)d_in[0];
    const float* coord   = (const float*)d_in[1];
    const int*   segment = (const int*)d_in[2];
    const int*   offset  = (const int*)d_in[3];
    const int n  = in_sizes[2];
    const int nb = in_sizes[3];
    unsigned* ws = (unsigned*)d_ws;

    hipLaunchKernelGGL(k_stats, dim3(NB), dim3(T), 0, stream,
                       coord, segment, offset, ws, n, nb);
    hipLaunchKernelGGL(k_loss, dim3(NB), dim3(T), 0, stream,
                       pred, coord, segment, offset, ws, n, nb);
    hipLaunchKernelGGL(k_final, dim3(1), dim3(NB), 0, stream,
                       ws, (float*)d_out, n);
}